// Round 2
// baseline (346.264 us; speedup 1.0000x reference)
//
#include <hip/hip_runtime.h>

#define NN 50000
#define IN_DIM 128
#define HD 96
#define BN_EPS 1e-5f
#define PN_SCALE 20.0f
#define SCAN_NB 196   // ceil(50000/256)

__device__ __forceinline__ float4 ld4(const float* p) { return *(const float4*)p; }
__device__ __forceinline__ float4 add4(float4 a, float4 b) {
    return make_float4(a.x + b.x, a.y + b.y, a.z + b.z, a.w + b.w);
}

// ---------------- zero stats + CSR counters ----------------
__global__ void zero_kernel(float* stats, int* cnt) {
    int i = blockIdx.x * blockDim.x + threadIdx.x;
    if (i < 1024) stats[i] = 0.0f;
    int j = i - 1024;
    if (j >= 0 && j < NN) cnt[j] = 0;
}

// ---------------- tiled GEMM: C[N,96] = act(A[N,K]) @ W[96,K]^T + b ----------
template<int K, int MODE>
__global__ __launch_bounds__(256) void gemm_tiled(
    const float* A, const float* __restrict__ W, const float* __restrict__ bias,
    float* out, const float* __restrict__ scale, const float* __restrict__ shift,
    float* __restrict__ gsum, float* __restrict__ gsumsq,
    float* __restrict__ gcol, float* __restrict__ growss)
{
    constexpr int CK = 32;
    __shared__ float sh[64 * (CK + 1) + HD * (CK + 1)];   // 5280 floats
    float* As = sh;
    float* Ws = sh + 64 * (CK + 1);

    const int t  = threadIdx.x;
    const int tx = t & 15;        // cols tx*6 .. tx*6+5
    const int ty = t >> 4;        // rows ty*4 .. ty*4+3
    const int base = blockIdx.x * 64;

    float acc[4][6];
#pragma unroll
    for (int i = 0; i < 4; ++i)
#pragma unroll
        for (int j = 0; j < 6; ++j) acc[i][j] = 0.0f;

    for (int kc = 0; kc < K; kc += CK) {
#pragma unroll
        for (int it = 0; it < 2; ++it) {
            int q = t + it * 256;
            int r = q >> 3, c4 = q & 7;
            int row = base + r;
            float4 v = make_float4(0.f, 0.f, 0.f, 0.f);
            if (row < NN) v = ld4(A + (size_t)row * K + kc + c4 * 4);
            if (MODE == 2) {
                float4 sc = ld4(scale + kc + c4 * 4);
                float4 shf = ld4(shift + kc + c4 * 4);
                v.x = fmaxf(v.x * sc.x + shf.x, 0.f);
                v.y = fmaxf(v.y * sc.y + shf.y, 0.f);
                v.z = fmaxf(v.z * sc.z + shf.z, 0.f);
                v.w = fmaxf(v.w * sc.w + shf.w, 0.f);
            }
            float* d = As + r * (CK + 1) + c4 * 4;
            d[0] = v.x; d[1] = v.y; d[2] = v.z; d[3] = v.w;
        }
#pragma unroll
        for (int it = 0; it < 3; ++it) {
            int q = t + it * 256;
            int r = q >> 3, c4 = q & 7;
            float4 v = ld4(W + (size_t)r * K + kc + c4 * 4);
            float* d = Ws + r * (CK + 1) + c4 * 4;
            d[0] = v.x; d[1] = v.y; d[2] = v.z; d[3] = v.w;
        }
        __syncthreads();
#pragma unroll
        for (int kk = 0; kk < CK; ++kk) {
            float a[4], b[6];
#pragma unroll
            for (int i = 0; i < 4; ++i) a[i] = As[(ty * 4 + i) * (CK + 1) + kk];
#pragma unroll
            for (int j = 0; j < 6; ++j) b[j] = Ws[(tx * 6 + j) * (CK + 1) + kk];
#pragma unroll
            for (int i = 0; i < 4; ++i)
#pragma unroll
                for (int j = 0; j < 6; ++j) acc[i][j] += a[i] * b[j];
        }
        __syncthreads();
    }

    float cv[4][6];
#pragma unroll
    for (int j = 0; j < 6; ++j) {
        float bs = bias[tx * 6 + j];
#pragma unroll
        for (int i = 0; i < 4; ++i) cv[i][j] = acc[i][j] + bs;
    }
#pragma unroll
    for (int i = 0; i < 4; ++i) {
        int row = base + ty * 4 + i;
        if (row < NN) {
#pragma unroll
            for (int j = 0; j < 6; ++j)
                out[(size_t)row * HD + tx * 6 + j] = cv[i][j];
        }
    }

    if (MODE == 1) {
        float* rs_sum = sh;            // [16][96]
        float* rs_sq  = sh + 1536;     // [16][96]
        __syncthreads();
#pragma unroll
        for (int j = 0; j < 6; ++j) {
            float s = 0.f, q = 0.f;
#pragma unroll
            for (int i = 0; i < 4; ++i) {
                int row = base + ty * 4 + i;
                float v = (row < NN) ? cv[i][j] : 0.f;
                s += v; q += v * v;
            }
            rs_sum[ty * HD + tx * 6 + j] = s;
            rs_sq[ty * HD + tx * 6 + j]  = q;
        }
        __syncthreads();
        if (t < HD) {
            float S = 0.f, Q = 0.f;
#pragma unroll
            for (int r = 0; r < 16; ++r) { S += rs_sum[r * HD + t]; Q += rs_sq[r * HD + t]; }
            atomicAdd(&gsum[t], S);
            atomicAdd(&gsumsq[t], Q);
        }
    }

    if (MODE == 2) {
        float* rs_sum = sh;            // [16][96]
        float* rr     = sh + 1536;     // [64][16]
        __syncthreads();
#pragma unroll
        for (int j = 0; j < 6; ++j) {
            float s = 0.f;
#pragma unroll
            for (int i = 0; i < 4; ++i) {
                int row = base + ty * 4 + i;
                s += (row < NN) ? cv[i][j] : 0.f;
            }
            rs_sum[ty * HD + tx * 6 + j] = s;
        }
#pragma unroll
        for (int i = 0; i < 4; ++i) {
            float q = 0.f;
#pragma unroll
            for (int j = 0; j < 6; ++j) q += cv[i][j] * cv[i][j];
            rr[(ty * 4 + i) * 16 + tx] = q;
        }
        __syncthreads();
        if (t < HD) {
            float S = 0.f;
#pragma unroll
            for (int r = 0; r < 16; ++r) S += rs_sum[r * HD + t];
            atomicAdd(&gcol[t], S);
        }
        if (t < 64) {
            int row = base + t;
            if (row < NN) {
                float S = 0.f;
#pragma unroll
                for (int g = 0; g < 16; ++g) S += rr[t * 16 + g];
                growss[row] = S;
            }
        }
    }
}

// ---------------- CSR build ----------------
__global__ void hist_kernel(const int* __restrict__ ei, int* __restrict__ cnt, int E) {
    int e = blockIdx.x * blockDim.x + threadIdx.x;
    if (e < E) atomicAdd(&cnt[ei[E + e]], 1);
}

__global__ __launch_bounds__(256) void scan_part1(const int* __restrict__ cnt,
                                                  int* __restrict__ bsum) {
    __shared__ int sh[256];
    int i = blockIdx.x * 256 + threadIdx.x;
    int t = threadIdx.x;
    sh[t] = (i < NN) ? cnt[i] : 0;
    __syncthreads();
    for (int off = 128; off > 0; off >>= 1) {
        if (t < off) sh[t] += sh[t + off];
        __syncthreads();
    }
    if (t == 0) bsum[blockIdx.x] = sh[0];
}

__global__ __launch_bounds__(256) void scan_part2(int* __restrict__ bsum) {
    __shared__ int sh[256];
    int t = threadIdx.x;
    int v = (t < SCAN_NB) ? bsum[t] : 0;
    sh[t] = v;
    __syncthreads();
    for (int off = 1; off < 256; off <<= 1) {
        int u = sh[t];
        if (t >= off) u += sh[t - off];
        __syncthreads();
        sh[t] = u;
        __syncthreads();
    }
    if (t < SCAN_NB) bsum[t] = sh[t] - v;    // exclusive block offsets
}

__global__ __launch_bounds__(256) void scan_part3(int* __restrict__ cnt,
                                                  const int* __restrict__ bsum,
                                                  int* __restrict__ rowptr) {
    __shared__ int sh[256];
    int i = blockIdx.x * 256 + threadIdx.x;
    int t = threadIdx.x;
    int v = (i < NN) ? cnt[i] : 0;
    sh[t] = v;
    __syncthreads();
    for (int off = 1; off < 256; off <<= 1) {
        int u = sh[t];
        if (t >= off) u += sh[t - off];
        __syncthreads();
        sh[t] = u;
        __syncthreads();
    }
    int excl = sh[t] - v + bsum[blockIdx.x];
    if (i < NN) { rowptr[i] = excl; cnt[i] = excl; }   // cnt becomes fill cursor
    if (i == NN - 1) rowptr[NN] = excl + v;
}

// fill: one edge per thread. 800K threads -> max outstanding atomic->store
// chains (latency-bound op, 12% HBM: write amplification is not the wall;
// outstanding-request count is). No multipass: pass loop serialized chains 7x.
__global__ __launch_bounds__(256) void fill_kernel(const int* __restrict__ ei,
                                                   int* __restrict__ cursor,
                                                   int* __restrict__ srcs, int E) {
    int e = blockIdx.x * 256 + threadIdx.x;
    if (e >= E) return;
    int dst = ei[E + e];
    int src = ei[e];
    int slot = atomicAdd(&cursor[dst], 1);
    srcs[slot] = src;
}

// -------- gather: z[i] = h0[i] + sum_{e:dst=i} h0[src_e] --------------------
// One 24-lane group owns a full row (24 x float4 = 96 floats). No LDS, no
// __syncthreads: waves retire independently, 8-deep load batches give MLP.
// 192-thread blocks (8 rows, 3 waves) -> ~10 blocks/CU resident.
__global__ __launch_bounds__(192) void gather_kernel(
    const float* __restrict__ h0, const int* __restrict__ rowptr,
    const int* __restrict__ srcs, float* __restrict__ z)
{
    const int tid = threadIdx.x;
    const int rl  = tid / 24;          // 0..7 local row
    const int c   = tid - rl * 24;     // 0..23 float4 lane
    const int row = blockIdx.x * 8 + rl;
    if (row >= NN) return;

    const int p0 = rowptr[row];
    const int p1 = rowptr[row + 1];

    float4 acc = ld4(h0 + (size_t)row * HD + c * 4);

    int p = p0;
    for (; p + 8 <= p1; p += 8) {
        int s0 = srcs[p + 0], s1 = srcs[p + 1], s2 = srcs[p + 2], s3 = srcs[p + 3];
        int s4 = srcs[p + 4], s5 = srcs[p + 5], s6 = srcs[p + 6], s7 = srcs[p + 7];
        float4 v0 = ld4(h0 + (size_t)s0 * HD + c * 4);
        float4 v1 = ld4(h0 + (size_t)s1 * HD + c * 4);
        float4 v2 = ld4(h0 + (size_t)s2 * HD + c * 4);
        float4 v3 = ld4(h0 + (size_t)s3 * HD + c * 4);
        float4 v4 = ld4(h0 + (size_t)s4 * HD + c * 4);
        float4 v5 = ld4(h0 + (size_t)s5 * HD + c * 4);
        float4 v6 = ld4(h0 + (size_t)s6 * HD + c * 4);
        float4 v7 = ld4(h0 + (size_t)s7 * HD + c * 4);
        acc = add4(acc, add4(add4(add4(v0, v1), add4(v2, v3)),
                             add4(add4(v4, v5), add4(v6, v7))));
    }
    for (; p + 4 <= p1; p += 4) {
        int s0 = srcs[p + 0], s1 = srcs[p + 1], s2 = srcs[p + 2], s3 = srcs[p + 3];
        float4 v0 = ld4(h0 + (size_t)s0 * HD + c * 4);
        float4 v1 = ld4(h0 + (size_t)s1 * HD + c * 4);
        float4 v2 = ld4(h0 + (size_t)s2 * HD + c * 4);
        float4 v3 = ld4(h0 + (size_t)s3 * HD + c * 4);
        acc = add4(acc, add4(add4(v0, v1), add4(v2, v3)));
    }
    for (; p < p1; ++p)
        acc = add4(acc, ld4(h0 + (size_t)srcs[p] * HD + c * 4));

    *(float4*)(z + (size_t)row * HD + c * 4) = acc;
}

__global__ void bn_finalize_kernel(const float* __restrict__ sum, const float* __restrict__ sumsq,
                                   const float* __restrict__ gamma, const float* __restrict__ beta,
                                   float* __restrict__ scale, float* __restrict__ shift)
{
    int f = threadIdx.x;
    if (f < HD) {
        float mean = sum[f] * (1.0f / NN);
        float var  = fmaxf(sumsq[f] * (1.0f / NN) - mean * mean, 0.0f);
        float rstd = rsqrtf(var + BN_EPS);
        float sc = rstd * gamma[f];
        scale[f] = sc;
        shift[f] = beta[f] - mean * sc;
    }
}

// ---------------- PairNorm: streaming float4, in place ----------------
__global__ __launch_bounds__(256) void pn_kernel(float* l1, const float* __restrict__ colsum,
                                                 const float* __restrict__ rowss)
{
    int idx = blockIdx.x * 256 + threadIdx.x;   // float4 index
    if (idx >= NN * 24) return;
    int row = idx / 24;
    int q = idx - row * 24;
    float rs = rsqrtf(1e-6f + rowss[row]);
    float4 v = ld4(l1 + (size_t)idx * 4);
    float4 cm = ld4(colsum + q * 4);
    v.x = PN_SCALE * v.x * rs - cm.x * (1.0f / NN);
    v.y = PN_SCALE * v.y * rs - cm.y * (1.0f / NN);
    v.z = PN_SCALE * v.z * rs - cm.z * (1.0f / NN);
    v.w = PN_SCALE * v.w * rs - cm.w * (1.0f / NN);
    *(float4*)(l1 + (size_t)idx * 4) = v;
}

extern "C" void kernel_launch(void* const* d_in, const int* in_sizes, int n_in,
                              void* d_out, int out_size, void* d_ws, size_t ws_size,
                              hipStream_t stream) {
    const float* x     = (const float*)d_in[0];
    const int*   ei    = (const int*)d_in[1];
    const float* W0    = (const float*)d_in[2];
    const float* b0    = (const float*)d_in[3];
    const float* W1    = (const float*)d_in[4];
    const float* b1    = (const float*)d_in[5];
    const float* gamma = (const float*)d_in[6];
    const float* beta  = (const float*)d_in[7];
    const float* W2    = (const float*)d_in[8];
    const float* b2    = (const float*)d_in[9];

    float* out_l1 = (float*)d_out;                 // [N,96]: z -> h -> l1 (in place)
    float* out_h0 = out_l1 + (size_t)NN * HD;      // [N,96]: h0 output

    float* stats   = (float*)d_ws;
    float* s_sum   = stats;            // 96
    float* s_sumsq = stats + HD;       // 96
    float* s_col   = stats + 2 * HD;   // 96
    float* s_scale = stats + 288;      // 96
    float* s_shift = stats + 384;      // 96
    float* rowss = stats + 1024;
    int* cnt    = (int*)(rowss + NN);
    int* rowptr = cnt + NN;
    int* bsum   = rowptr + NN + 2;
    int* srcs   = bsum + 256;

    const int E = in_sizes[1] / 2;                 // 800000
    const int GB = (NN + 63) / 64;                 // 782

    zero_kernel<<<(1024 + NN + 255) / 256, 256, 0, stream>>>(stats, cnt);
    // 1) h0 = x @ W0^T + b0
    gemm_tiled<IN_DIM, 0><<<GB, 256, 0, stream>>>(x, W0, b0, out_h0, nullptr, nullptr,
                                                  nullptr, nullptr, nullptr, nullptr);
    // 2) CSR build: histogram -> hierarchical scan -> one-edge-per-thread fill
    hist_kernel<<<(E + 255) / 256, 256, 0, stream>>>(ei, cnt, E);
    scan_part1<<<SCAN_NB, 256, 0, stream>>>(cnt, bsum);
    scan_part2<<<1, 256, 0, stream>>>(bsum);
    scan_part3<<<SCAN_NB, 256, 0, stream>>>(cnt, bsum, rowptr);
    fill_kernel<<<(E + 255) / 256, 256, 0, stream>>>(ei, cnt, srcs, E);
    // 3) gather: z = h0 + segment_sum(h0[src])
    gather_kernel<<<(NN + 7) / 8, 192, 0, stream>>>(out_h0, rowptr, srcs, out_l1);
    // 4) h = z @ W1^T + b1 (in place) + fused BN stats
    gemm_tiled<HD, 1><<<GB, 256, 0, stream>>>(out_l1, W1, b1, out_l1, nullptr, nullptr,
                                              s_sum, s_sumsq, nullptr, nullptr);
    bn_finalize_kernel<<<1, 128, 0, stream>>>(s_sum, s_sumsq, gamma, beta, s_scale, s_shift);
    // 5) l1 = relu(bn(h)) @ W2^T + b2 (in place) + fused PN stats
    gemm_tiled<HD, 2><<<GB, 256, 0, stream>>>(out_l1, W2, b2, out_l1, s_scale, s_shift,
                                              nullptr, nullptr, s_col, rowss);
    // 6) PairNorm finalize (streaming, in place)
    pn_kernel<<<(NN * 24 + 255) / 256, 256, 0, stream>>>(out_l1, s_col, rowss);
}

// Round 3
// 337.622 us; speedup vs baseline: 1.0256x; 1.0256x over previous
//
#include <hip/hip_runtime.h>

#define NN 50000
#define IN_DIM 128
#define HD 96
#define BN_EPS 1e-5f
#define PN_SCALE 20.0f
#define SCAN_NB 196   // ceil(50000/256)

__device__ __forceinline__ float4 ld4(const float* p) { return *(const float4*)p; }
__device__ __forceinline__ float4 add4(float4 a, float4 b) {
    return make_float4(a.x + b.x, a.y + b.y, a.z + b.z, a.w + b.w);
}

// ---------------- zero stats + CSR counters ----------------
__global__ void zero_kernel(float* stats, int* cnt) {
    int i = blockIdx.x * blockDim.x + threadIdx.x;
    if (i < 1024) stats[i] = 0.0f;
    int j = i - 1024;
    if (j >= 0 && j < NN) cnt[j] = 0;
}

// ---------------- tiled GEMM: C[N,96] = act(A[N,K]) @ W[96,K]^T + b ----------
// MODE 0 additionally runs the edge histogram as a prologue: the 800K
// fire-and-forget atomics drain under the GEMM K-loop instead of costing a
// standalone latency-bound dispatch (stream serializes all kernels).
template<int K, int MODE>
__global__ __launch_bounds__(256) void gemm_tiled(
    const float* A, const float* __restrict__ W, const float* __restrict__ bias,
    float* out, const float* __restrict__ scale, const float* __restrict__ shift,
    float* __restrict__ gsum, float* __restrict__ gsumsq,
    float* __restrict__ gcol, float* __restrict__ growss,
    const int* __restrict__ hist_dst, int* __restrict__ hist_cnt, int histE)
{
    constexpr int CK = 32;
    __shared__ float sh[64 * (CK + 1) + HD * (CK + 1)];   // 5280 floats
    float* As = sh;
    float* Ws = sh + 64 * (CK + 1);

    const int t  = threadIdx.x;

    if (MODE == 0) {
        int e0 = blockIdx.x * 1024 + t * 4;
#pragma unroll
        for (int i = 0; i < 4; ++i) {
            int e = e0 + i;
            if (e < histE) atomicAdd(&hist_cnt[hist_dst[e]], 1);
        }
    }

    const int tx = t & 15;        // cols tx*6 .. tx*6+5
    const int ty = t >> 4;        // rows ty*4 .. ty*4+3
    const int base = blockIdx.x * 64;

    float acc[4][6];
#pragma unroll
    for (int i = 0; i < 4; ++i)
#pragma unroll
        for (int j = 0; j < 6; ++j) acc[i][j] = 0.0f;

    for (int kc = 0; kc < K; kc += CK) {
#pragma unroll
        for (int it = 0; it < 2; ++it) {
            int q = t + it * 256;
            int r = q >> 3, c4 = q & 7;
            int row = base + r;
            float4 v = make_float4(0.f, 0.f, 0.f, 0.f);
            if (row < NN) v = ld4(A + (size_t)row * K + kc + c4 * 4);
            if (MODE == 2) {
                float4 sc = ld4(scale + kc + c4 * 4);
                float4 shf = ld4(shift + kc + c4 * 4);
                v.x = fmaxf(v.x * sc.x + shf.x, 0.f);
                v.y = fmaxf(v.y * sc.y + shf.y, 0.f);
                v.z = fmaxf(v.z * sc.z + shf.z, 0.f);
                v.w = fmaxf(v.w * sc.w + shf.w, 0.f);
            }
            float* d = As + r * (CK + 1) + c4 * 4;
            d[0] = v.x; d[1] = v.y; d[2] = v.z; d[3] = v.w;
        }
#pragma unroll
        for (int it = 0; it < 3; ++it) {
            int q = t + it * 256;
            int r = q >> 3, c4 = q & 7;
            float4 v = ld4(W + (size_t)r * K + kc + c4 * 4);
            float* d = Ws + r * (CK + 1) + c4 * 4;
            d[0] = v.x; d[1] = v.y; d[2] = v.z; d[3] = v.w;
        }
        __syncthreads();
#pragma unroll
        for (int kk = 0; kk < CK; ++kk) {
            float a[4], b[6];
#pragma unroll
            for (int i = 0; i < 4; ++i) a[i] = As[(ty * 4 + i) * (CK + 1) + kk];
#pragma unroll
            for (int j = 0; j < 6; ++j) b[j] = Ws[(tx * 6 + j) * (CK + 1) + kk];
#pragma unroll
            for (int i = 0; i < 4; ++i)
#pragma unroll
                for (int j = 0; j < 6; ++j) acc[i][j] += a[i] * b[j];
        }
        __syncthreads();
    }

    float cv[4][6];
#pragma unroll
    for (int j = 0; j < 6; ++j) {
        float bs = bias[tx * 6 + j];
#pragma unroll
        for (int i = 0; i < 4; ++i) cv[i][j] = acc[i][j] + bs;
    }
#pragma unroll
    for (int i = 0; i < 4; ++i) {
        int row = base + ty * 4 + i;
        if (row < NN) {
#pragma unroll
            for (int j = 0; j < 6; ++j)
                out[(size_t)row * HD + tx * 6 + j] = cv[i][j];
        }
    }

    if (MODE == 1) {
        float* rs_sum = sh;            // [16][96]
        float* rs_sq  = sh + 1536;     // [16][96]
        __syncthreads();
#pragma unroll
        for (int j = 0; j < 6; ++j) {
            float s = 0.f, q = 0.f;
#pragma unroll
            for (int i = 0; i < 4; ++i) {
                int row = base + ty * 4 + i;
                float v = (row < NN) ? cv[i][j] : 0.f;
                s += v; q += v * v;
            }
            rs_sum[ty * HD + tx * 6 + j] = s;
            rs_sq[ty * HD + tx * 6 + j]  = q;
        }
        __syncthreads();
        if (t < HD) {
            float S = 0.f, Q = 0.f;
#pragma unroll
            for (int r = 0; r < 16; ++r) { S += rs_sum[r * HD + t]; Q += rs_sq[r * HD + t]; }
            atomicAdd(&gsum[t], S);
            atomicAdd(&gsumsq[t], Q);
        }
    }

    if (MODE == 2) {
        float* rs_sum = sh;            // [16][96]
        float* rr     = sh + 1536;     // [64][16]
        __syncthreads();
#pragma unroll
        for (int j = 0; j < 6; ++j) {
            float s = 0.f;
#pragma unroll
            for (int i = 0; i < 4; ++i) {
                int row = base + ty * 4 + i;
                s += (row < NN) ? cv[i][j] : 0.f;
            }
            rs_sum[ty * HD + tx * 6 + j] = s;
        }
#pragma unroll
        for (int i = 0; i < 4; ++i) {
            float q = 0.f;
#pragma unroll
            for (int j = 0; j < 6; ++j) q += cv[i][j] * cv[i][j];
            rr[(ty * 4 + i) * 16 + tx] = q;
        }
        __syncthreads();
        if (t < HD) {
            float S = 0.f;
#pragma unroll
            for (int r = 0; r < 16; ++r) S += rs_sum[r * HD + t];
            atomicAdd(&gcol[t], S);
        }
        if (t < 64) {
            int row = base + t;
            if (row < NN) {
                float S = 0.f;
#pragma unroll
                for (int g = 0; g < 16; ++g) S += rr[t * 16 + g];
                growss[row] = S;
            }
        }
    }
}

// ---------------- CSR build ----------------
__global__ __launch_bounds__(256) void scan_part1(const int* __restrict__ cnt,
                                                  int* __restrict__ bsum) {
    __shared__ int sh[256];
    int i = blockIdx.x * 256 + threadIdx.x;
    int t = threadIdx.x;
    sh[t] = (i < NN) ? cnt[i] : 0;
    __syncthreads();
    for (int off = 128; off > 0; off >>= 1) {
        if (t < off) sh[t] += sh[t + off];
        __syncthreads();
    }
    if (t == 0) bsum[blockIdx.x] = sh[0];
}

__global__ __launch_bounds__(256) void scan_part2(int* __restrict__ bsum) {
    __shared__ int sh[256];
    int t = threadIdx.x;
    int v = (t < SCAN_NB) ? bsum[t] : 0;
    sh[t] = v;
    __syncthreads();
    for (int off = 1; off < 256; off <<= 1) {
        int u = sh[t];
        if (t >= off) u += sh[t - off];
        __syncthreads();
        sh[t] = u;
        __syncthreads();
    }
    if (t < SCAN_NB) bsum[t] = sh[t] - v;    // exclusive block offsets
}

__global__ __launch_bounds__(256) void scan_part3(int* __restrict__ cnt,
                                                  const int* __restrict__ bsum,
                                                  int* __restrict__ rowptr) {
    __shared__ int sh[256];
    int i = blockIdx.x * 256 + threadIdx.x;
    int t = threadIdx.x;
    int v = (i < NN) ? cnt[i] : 0;
    sh[t] = v;
    __syncthreads();
    for (int off = 1; off < 256; off <<= 1) {
        int u = sh[t];
        if (t >= off) u += sh[t - off];
        __syncthreads();
        sh[t] = u;
        __syncthreads();
    }
    int excl = sh[t] - v + bsum[blockIdx.x];
    if (i < NN) { rowptr[i] = excl; cnt[i] = excl; }   // cnt becomes fill cursor
    if (i == NN - 1) rowptr[NN] = excl + v;
}

// fill with dst-range multipass: clusters slot-writes of a row in time so the
// srcs write window per pass (~460 KB) stays L2-resident -> line coalescing.
// (Round-1 A/B: removing the pass clustering raised WRITE_SIZE 40->52.6 MB and
// slowed fill 46.5->55 us despite 2x occupancy -> clustering is load-bearing.)
// 2 edges/thread (vs 4) doubles resident chains while keeping clustering.
__global__ __launch_bounds__(256) void fill_kernel(const int* __restrict__ ei,
                                                   int* __restrict__ cursor,
                                                   int* __restrict__ srcs, int E) {
    int t2 = blockIdx.x * 256 + threadIdx.x;
    int e0 = t2 * 2;
    int src[2], dst[2];
#pragma unroll
    for (int i = 0; i < 2; ++i) {
        int e = e0 + i;
        bool ok = e < E;
        dst[i] = ok ? ei[E + e] : -1;
        src[i] = ok ? ei[e] : 0;
    }
    for (int pass = 0; pass < 7; ++pass) {
#pragma unroll
        for (int i = 0; i < 2; ++i) {
            if (dst[i] >= 0 && (dst[i] >> 13) == pass) {
                int slot = atomicAdd(&cursor[dst[i]], 1);
                srcs[slot] = src[i];
            }
        }
    }
}

// -------- gather: z[i] = h0[i] + sum_{e:dst=i} h0[src_e] --------------------
// One 24-lane group owns a full row (24 x float4 = 96 floats). No LDS, no
// __syncthreads: waves retire independently, 8-deep load batches give MLP.
__global__ __launch_bounds__(192) void gather_kernel(
    const float* __restrict__ h0, const int* __restrict__ rowptr,
    const int* __restrict__ srcs, float* __restrict__ z)
{
    const int tid = threadIdx.x;
    const int rl  = tid / 24;          // 0..7 local row
    const int c   = tid - rl * 24;     // 0..23 float4 lane
    const int row = blockIdx.x * 8 + rl;
    if (row >= NN) return;

    const int p0 = rowptr[row];
    const int p1 = rowptr[row + 1];

    float4 acc = ld4(h0 + (size_t)row * HD + c * 4);

    int p = p0;
    for (; p + 8 <= p1; p += 8) {
        int s0 = srcs[p + 0], s1 = srcs[p + 1], s2 = srcs[p + 2], s3 = srcs[p + 3];
        int s4 = srcs[p + 4], s5 = srcs[p + 5], s6 = srcs[p + 6], s7 = srcs[p + 7];
        float4 v0 = ld4(h0 + (size_t)s0 * HD + c * 4);
        float4 v1 = ld4(h0 + (size_t)s1 * HD + c * 4);
        float4 v2 = ld4(h0 + (size_t)s2 * HD + c * 4);
        float4 v3 = ld4(h0 + (size_t)s3 * HD + c * 4);
        float4 v4 = ld4(h0 + (size_t)s4 * HD + c * 4);
        float4 v5 = ld4(h0 + (size_t)s5 * HD + c * 4);
        float4 v6 = ld4(h0 + (size_t)s6 * HD + c * 4);
        float4 v7 = ld4(h0 + (size_t)s7 * HD + c * 4);
        acc = add4(acc, add4(add4(add4(v0, v1), add4(v2, v3)),
                             add4(add4(v4, v5), add4(v6, v7))));
    }
    for (; p + 4 <= p1; p += 4) {
        int s0 = srcs[p + 0], s1 = srcs[p + 1], s2 = srcs[p + 2], s3 = srcs[p + 3];
        float4 v0 = ld4(h0 + (size_t)s0 * HD + c * 4);
        float4 v1 = ld4(h0 + (size_t)s1 * HD + c * 4);
        float4 v2 = ld4(h0 + (size_t)s2 * HD + c * 4);
        float4 v3 = ld4(h0 + (size_t)s3 * HD + c * 4);
        acc = add4(acc, add4(add4(v0, v1), add4(v2, v3)));
    }
    for (; p < p1; ++p)
        acc = add4(acc, ld4(h0 + (size_t)srcs[p] * HD + c * 4));

    *(float4*)(z + (size_t)row * HD + c * 4) = acc;
}

__global__ void bn_finalize_kernel(const float* __restrict__ sum, const float* __restrict__ sumsq,
                                   const float* __restrict__ gamma, const float* __restrict__ beta,
                                   float* __restrict__ scale, float* __restrict__ shift)
{
    int f = threadIdx.x;
    if (f < HD) {
        float mean = sum[f] * (1.0f / NN);
        float var  = fmaxf(sumsq[f] * (1.0f / NN) - mean * mean, 0.0f);
        float rstd = rsqrtf(var + BN_EPS);
        float sc = rstd * gamma[f];
        scale[f] = sc;
        shift[f] = beta[f] - mean * sc;
    }
}

// ---------------- PairNorm: streaming float4, in place ----------------
__global__ __launch_bounds__(256) void pn_kernel(float* l1, const float* __restrict__ colsum,
                                                 const float* __restrict__ rowss)
{
    int idx = blockIdx.x * 256 + threadIdx.x;   // float4 index
    if (idx >= NN * 24) return;
    int row = idx / 24;
    int q = idx - row * 24;
    float rs = rsqrtf(1e-6f + rowss[row]);
    float4 v = ld4(l1 + (size_t)idx * 4);
    float4 cm = ld4(colsum + q * 4);
    v.x = PN_SCALE * v.x * rs - cm.x * (1.0f / NN);
    v.y = PN_SCALE * v.y * rs - cm.y * (1.0f / NN);
    v.z = PN_SCALE * v.z * rs - cm.z * (1.0f / NN);
    v.w = PN_SCALE * v.w * rs - cm.w * (1.0f / NN);
    *(float4*)(l1 + (size_t)idx * 4) = v;
}

extern "C" void kernel_launch(void* const* d_in, const int* in_sizes, int n_in,
                              void* d_out, int out_size, void* d_ws, size_t ws_size,
                              hipStream_t stream) {
    const float* x     = (const float*)d_in[0];
    const int*   ei    = (const int*)d_in[1];
    const float* W0    = (const float*)d_in[2];
    const float* b0    = (const float*)d_in[3];
    const float* W1    = (const float*)d_in[4];
    const float* b1    = (const float*)d_in[5];
    const float* gamma = (const float*)d_in[6];
    const float* beta  = (const float*)d_in[7];
    const float* W2    = (const float*)d_in[8];
    const float* b2    = (const float*)d_in[9];

    float* out_l1 = (float*)d_out;                 // [N,96]: z -> h -> l1 (in place)
    float* out_h0 = out_l1 + (size_t)NN * HD;      // [N,96]: h0 output

    float* stats   = (float*)d_ws;
    float* s_sum   = stats;            // 96
    float* s_sumsq = stats + HD;       // 96
    float* s_col   = stats + 2 * HD;   // 96
    float* s_scale = stats + 288;      // 96
    float* s_shift = stats + 384;      // 96
    float* rowss = stats + 1024;
    int* cnt    = (int*)(rowss + NN);
    int* rowptr = cnt + NN;
    int* bsum   = rowptr + NN + 2;
    int* srcs   = bsum + 256;

    const int E = in_sizes[1] / 2;                 // 800000
    const int GB = (NN + 63) / 64;                 // 782

    zero_kernel<<<(1024 + NN + 255) / 256, 256, 0, stream>>>(stats, cnt);
    // 1) h0 = x @ W0^T + b0, with edge histogram fused as prologue
    //    (782 blocks x 1024 edges covers E=800000; atomics drain under GEMM)
    gemm_tiled<IN_DIM, 0><<<GB, 256, 0, stream>>>(x, W0, b0, out_h0, nullptr, nullptr,
                                                  nullptr, nullptr, nullptr, nullptr,
                                                  ei + E, cnt, E);
    // 2) CSR build: hierarchical scan -> multipass fill
    scan_part1<<<SCAN_NB, 256, 0, stream>>>(cnt, bsum);
    scan_part2<<<1, 256, 0, stream>>>(bsum);
    scan_part3<<<SCAN_NB, 256, 0, stream>>>(cnt, bsum, rowptr);
    fill_kernel<<<(E / 2 + 255) / 256, 256, 0, stream>>>(ei, cnt, srcs, E);
    // 3) gather: z = h0 + segment_sum(h0[src])
    gather_kernel<<<(NN + 7) / 8, 192, 0, stream>>>(out_h0, rowptr, srcs, out_l1);
    // 4) h = z @ W1^T + b1 (in place) + fused BN stats
    gemm_tiled<HD, 1><<<GB, 256, 0, stream>>>(out_l1, W1, b1, out_l1, nullptr, nullptr,
                                              s_sum, s_sumsq, nullptr, nullptr,
                                              nullptr, nullptr, 0);
    bn_finalize_kernel<<<1, 128, 0, stream>>>(s_sum, s_sumsq, gamma, beta, s_scale, s_shift);
    // 5) l1 = relu(bn(h)) @ W2^T + b2 (in place) + fused PN stats
    gemm_tiled<HD, 2><<<GB, 256, 0, stream>>>(out_l1, W2, b2, out_l1, s_scale, s_shift,
                                              nullptr, nullptr, s_col, rowss,
                                              nullptr, nullptr, 0);
    // 6) PairNorm finalize (streaming, in place)
    pn_kernel<<<(NN * 24 + 255) / 256, 256, 0, stream>>>(out_l1, s_col, rowss);
}

// Round 4
// 331.145 us; speedup vs baseline: 1.0457x; 1.0196x over previous
//
#include <hip/hip_runtime.h>

#define NN 50000
#define IN_DIM 128
#define HD 96
#define BN_EPS 1e-5f
#define PN_SCALE 20.0f
#define SCAN_NB 196   // ceil(50000/256)

__device__ __forceinline__ float4 ld4(const float* p) { return *(const float4*)p; }
__device__ __forceinline__ float4 add4(float4 a, float4 b) {
    return make_float4(a.x + b.x, a.y + b.y, a.z + b.z, a.w + b.w);
}

// ---------------- zero stats + CSR counters ----------------
__global__ void zero_kernel(float* stats, int* cnt) {
    int i = blockIdx.x * blockDim.x + threadIdx.x;
    if (i < 1024) stats[i] = 0.0f;
    int j = i - 1024;
    if (j >= 0 && j < NN) cnt[j] = 0;
}

// ---------------- tiled GEMM: C[N,96] = act(A[N,K]) @ W[96,K]^T + b ----------
// k-major LDS + vectorized fragment reads (1x b64 A + 3x b128 W per kk for 24
// FMAs) + register-staged prefetch (load chunk k+1 before computing chunk k)
// so HBM latency drains under compute instead of at the barrier.
// Thread map: 256 threads = 32 row-groups (2 rows) x 8 col-groups (12 cols).
// MODE 0 runs the edge histogram as a prologue (atomics drain under GEMM).
template<int K, int MODE>
__global__ __launch_bounds__(256) void gemm_tiled(
    const float* A, const float* __restrict__ W, const float* __restrict__ bias,
    float* out, const float* __restrict__ scale, const float* __restrict__ shift,
    float* __restrict__ gsum, float* __restrict__ gsumsq,
    float* __restrict__ gcol, float* __restrict__ growss,
    const int* __restrict__ hist_dst, int* __restrict__ hist_cnt, int histE)
{
    constexpr int CK  = 32;
    constexpr int APD = 66;    // As row pitch (64 + 2): b64-aligned, 2-way banks
    constexpr int WPD = 100;   // Ws row pitch (96 + 4): b128-aligned
    __shared__ float sh[32 * APD + 32 * WPD];   // 5312 floats = 21.2 KB
    float* As = sh;                 // [CK][APD] k-major
    float* Ws = sh + 32 * APD;      // [CK][WPD] k-major

    const int t  = threadIdx.x;

    if (MODE == 0) {
        int e0 = blockIdx.x * 1024 + t * 4;
#pragma unroll
        for (int i = 0; i < 4; ++i) {
            int e = e0 + i;
            if (e < histE) atomicAdd(&hist_cnt[hist_dst[e]], 1);
        }
    }

    const int ty = t >> 3;        // 0..31: rows ty*2, ty*2+1
    const int tx = t & 7;         // 0..7:  cols tx*12 .. +11
    const int base = blockIdx.x * 64;

    float acc[2][12];
#pragma unroll
    for (int i = 0; i < 2; ++i)
#pragma unroll
        for (int j = 0; j < 12; ++j) acc[i][j] = 0.0f;

    float4 pa[2], pw[3];

    auto load_stage = [&](int kc) {
#pragma unroll
        for (int it = 0; it < 2; ++it) {
            int q = t + it * 256;
            int r = q >> 3, c4 = q & 7;
            int row = base + r;
            pa[it] = (row < NN) ? ld4(A + (size_t)row * K + kc + c4 * 4)
                                : make_float4(0.f, 0.f, 0.f, 0.f);
        }
#pragma unroll
        for (int it = 0; it < 3; ++it) {
            int q = t + it * 256;
            int r = q >> 3, c4 = q & 7;       // r < 96
            pw[it] = ld4(W + (size_t)r * K + kc + c4 * 4);
        }
    };

    auto write_stage = [&](int kc) {
#pragma unroll
        for (int it = 0; it < 2; ++it) {
            int q = t + it * 256;
            int r = q >> 3, c4 = q & 7;
            float4 v = pa[it];
            if (MODE == 2) {
                float4 sc  = ld4(scale + kc + c4 * 4);
                float4 shf = ld4(shift + kc + c4 * 4);
                v.x = fmaxf(v.x * sc.x + shf.x, 0.f);
                v.y = fmaxf(v.y * sc.y + shf.y, 0.f);
                v.z = fmaxf(v.z * sc.z + shf.z, 0.f);
                v.w = fmaxf(v.w * sc.w + shf.w, 0.f);
            }
            As[(c4 * 4 + 0) * APD + r] = v.x;
            As[(c4 * 4 + 1) * APD + r] = v.y;
            As[(c4 * 4 + 2) * APD + r] = v.z;
            As[(c4 * 4 + 3) * APD + r] = v.w;
        }
#pragma unroll
        for (int it = 0; it < 3; ++it) {
            int q = t + it * 256;
            int r = q >> 3, c4 = q & 7;
            float4 v = pw[it];
            Ws[(c4 * 4 + 0) * WPD + r] = v.x;
            Ws[(c4 * 4 + 1) * WPD + r] = v.y;
            Ws[(c4 * 4 + 2) * WPD + r] = v.z;
            Ws[(c4 * 4 + 3) * WPD + r] = v.w;
        }
    };

    load_stage(0);
    for (int kc = 0; kc < K; kc += CK) {
        write_stage(kc);
        __syncthreads();
        if (kc + CK < K) load_stage(kc + CK);   // in flight during compute
#pragma unroll 8
        for (int kk = 0; kk < CK; ++kk) {
            float2 a = *(const float2*)(As + kk * APD + ty * 2);
            float4 w0 = ld4(Ws + kk * WPD + tx * 12);
            float4 w1 = ld4(Ws + kk * WPD + tx * 12 + 4);
            float4 w2 = ld4(Ws + kk * WPD + tx * 12 + 8);
            float av[2] = {a.x, a.y};
            float wv[12] = {w0.x, w0.y, w0.z, w0.w,
                            w1.x, w1.y, w1.z, w1.w,
                            w2.x, w2.y, w2.z, w2.w};
#pragma unroll
            for (int i = 0; i < 2; ++i)
#pragma unroll
                for (int j = 0; j < 12; ++j) acc[i][j] += av[i] * wv[j];
        }
        __syncthreads();
    }

    float cv[2][12];
    float4 b0v = ld4(bias + tx * 12);
    float4 b1v = ld4(bias + tx * 12 + 4);
    float4 b2v = ld4(bias + tx * 12 + 8);
    float bv[12] = {b0v.x, b0v.y, b0v.z, b0v.w,
                    b1v.x, b1v.y, b1v.z, b1v.w,
                    b2v.x, b2v.y, b2v.z, b2v.w};
#pragma unroll
    for (int i = 0; i < 2; ++i)
#pragma unroll
        for (int j = 0; j < 12; ++j) cv[i][j] = acc[i][j] + bv[j];

#pragma unroll
    for (int i = 0; i < 2; ++i) {
        int row = base + ty * 2 + i;
        if (row < NN) {
            float* o = out + (size_t)row * HD + tx * 12;
            *(float4*)(o + 0) = make_float4(cv[i][0], cv[i][1], cv[i][2],  cv[i][3]);
            *(float4*)(o + 4) = make_float4(cv[i][4], cv[i][5], cv[i][6],  cv[i][7]);
            *(float4*)(o + 8) = make_float4(cv[i][8], cv[i][9], cv[i][10], cv[i][11]);
        }
    }

    if (MODE == 1) {
        float* rs = sh;                       // [32][96] reuse
        // pass 1: col sums
        __syncthreads();
        {
            float s[12];
#pragma unroll
            for (int j = 0; j < 12; ++j) {
                s[j] = 0.f;
#pragma unroll
                for (int i = 0; i < 2; ++i) {
                    int row = base + ty * 2 + i;
                    s[j] += (row < NN) ? cv[i][j] : 0.f;
                }
            }
            float* d = rs + ty * HD + tx * 12;
            *(float4*)(d + 0) = make_float4(s[0], s[1], s[2],  s[3]);
            *(float4*)(d + 4) = make_float4(s[4], s[5], s[6],  s[7]);
            *(float4*)(d + 8) = make_float4(s[8], s[9], s[10], s[11]);
        }
        __syncthreads();
        if (t < HD) {
            float S = 0.f;
#pragma unroll
            for (int r = 0; r < 32; ++r) S += rs[r * HD + t];
            atomicAdd(&gsum[t], S);
        }
        __syncthreads();
        // pass 2: col sum-of-squares
        {
            float s[12];
#pragma unroll
            for (int j = 0; j < 12; ++j) {
                s[j] = 0.f;
#pragma unroll
                for (int i = 0; i < 2; ++i) {
                    int row = base + ty * 2 + i;
                    float v = (row < NN) ? cv[i][j] : 0.f;
                    s[j] += v * v;
                }
            }
            float* d = rs + ty * HD + tx * 12;
            *(float4*)(d + 0) = make_float4(s[0], s[1], s[2],  s[3]);
            *(float4*)(d + 4) = make_float4(s[4], s[5], s[6],  s[7]);
            *(float4*)(d + 8) = make_float4(s[8], s[9], s[10], s[11]);
        }
        __syncthreads();
        if (t < HD) {
            float Q = 0.f;
#pragma unroll
            for (int r = 0; r < 32; ++r) Q += rs[r * HD + t];
            atomicAdd(&gsumsq[t], Q);
        }
    }

    if (MODE == 2) {
        float* rs = sh;                       // [32][96] col sums
        float* rr = sh + 32 * HD;             // [64][8]  row sumsq partials
        __syncthreads();
        {
            float s[12];
#pragma unroll
            for (int j = 0; j < 12; ++j) {
                s[j] = 0.f;
#pragma unroll
                for (int i = 0; i < 2; ++i) {
                    int row = base + ty * 2 + i;
                    s[j] += (row < NN) ? cv[i][j] : 0.f;
                }
            }
            float* d = rs + ty * HD + tx * 12;
            *(float4*)(d + 0) = make_float4(s[0], s[1], s[2],  s[3]);
            *(float4*)(d + 4) = make_float4(s[4], s[5], s[6],  s[7]);
            *(float4*)(d + 8) = make_float4(s[8], s[9], s[10], s[11]);
#pragma unroll
            for (int i = 0; i < 2; ++i) {
                float q = 0.f;
#pragma unroll
                for (int j = 0; j < 12; ++j) q += cv[i][j] * cv[i][j];
                rr[(ty * 2 + i) * 8 + tx] = q;
            }
        }
        __syncthreads();
        if (t < HD) {
            float S = 0.f;
#pragma unroll
            for (int r = 0; r < 32; ++r) S += rs[r * HD + t];
            atomicAdd(&gcol[t], S);
        }
        if (t < 64) {
            int row = base + t;
            if (row < NN) {
                float S = 0.f;
#pragma unroll
                for (int g = 0; g < 8; ++g) S += rr[t * 8 + g];
                growss[row] = S;
            }
        }
    }
}

// ---------------- CSR build ----------------
__global__ __launch_bounds__(256) void scan_part1(const int* __restrict__ cnt,
                                                  int* __restrict__ bsum) {
    __shared__ int sh[256];
    int i = blockIdx.x * 256 + threadIdx.x;
    int t = threadIdx.x;
    sh[t] = (i < NN) ? cnt[i] : 0;
    __syncthreads();
    for (int off = 128; off > 0; off >>= 1) {
        if (t < off) sh[t] += sh[t + off];
        __syncthreads();
    }
    if (t == 0) bsum[blockIdx.x] = sh[0];
}

__global__ __launch_bounds__(256) void scan_part2(int* __restrict__ bsum) {
    __shared__ int sh[256];
    int t = threadIdx.x;
    int v = (t < SCAN_NB) ? bsum[t] : 0;
    sh[t] = v;
    __syncthreads();
    for (int off = 1; off < 256; off <<= 1) {
        int u = sh[t];
        if (t >= off) u += sh[t - off];
        __syncthreads();
        sh[t] = u;
        __syncthreads();
    }
    if (t < SCAN_NB) bsum[t] = sh[t] - v;    // exclusive block offsets
}

__global__ __launch_bounds__(256) void scan_part3(int* __restrict__ cnt,
                                                  const int* __restrict__ bsum,
                                                  int* __restrict__ rowptr) {
    __shared__ int sh[256];
    int i = blockIdx.x * 256 + threadIdx.x;
    int t = threadIdx.x;
    int v = (i < NN) ? cnt[i] : 0;
    sh[t] = v;
    __syncthreads();
    for (int off = 1; off < 256; off <<= 1) {
        int u = sh[t];
        if (t >= off) u += sh[t - off];
        __syncthreads();
        sh[t] = u;
        __syncthreads();
    }
    int excl = sh[t] - v + bsum[blockIdx.x];
    if (i < NN) { rowptr[i] = excl; cnt[i] = excl; }   // cnt becomes fill cursor
    if (i == NN - 1) rowptr[NN] = excl + v;
}

// fill with dst-range multipass: clusters slot-writes of a row in time so the
// srcs write window per pass (~460 KB) stays L2-resident -> line coalescing.
// (Round-1 A/B: removing the pass clustering raised WRITE_SIZE 40->52.6 MB and
// slowed fill 46.5->55 us despite 2x occupancy -> clustering is load-bearing.)
// 2 edges/thread keeps clustering with 2x the resident chains of 4/thread.
__global__ __launch_bounds__(256) void fill_kernel(const int* __restrict__ ei,
                                                   int* __restrict__ cursor,
                                                   int* __restrict__ srcs, int E) {
    int t2 = blockIdx.x * 256 + threadIdx.x;
    int e0 = t2 * 2;
    int src[2], dst[2];
#pragma unroll
    for (int i = 0; i < 2; ++i) {
        int e = e0 + i;
        bool ok = e < E;
        dst[i] = ok ? ei[E + e] : -1;
        src[i] = ok ? ei[e] : 0;
    }
    for (int pass = 0; pass < 7; ++pass) {
#pragma unroll
        for (int i = 0; i < 2; ++i) {
            if (dst[i] >= 0 && (dst[i] >> 13) == pass) {
                int slot = atomicAdd(&cursor[dst[i]], 1);
                srcs[slot] = src[i];
            }
        }
    }
}

// -------- gather: z[i] = h0[i] + sum_{e:dst=i} h0[src_e] --------------------
// One 24-lane group owns a full row (24 x float4 = 96 floats). No LDS, no
// __syncthreads: waves retire independently, 8-deep load batches give MLP.
__global__ __launch_bounds__(192) void gather_kernel(
    const float* __restrict__ h0, const int* __restrict__ rowptr,
    const int* __restrict__ srcs, float* __restrict__ z)
{
    const int tid = threadIdx.x;
    const int rl  = tid / 24;          // 0..7 local row
    const int c   = tid - rl * 24;     // 0..23 float4 lane
    const int row = blockIdx.x * 8 + rl;
    if (row >= NN) return;

    const int p0 = rowptr[row];
    const int p1 = rowptr[row + 1];

    float4 acc = ld4(h0 + (size_t)row * HD + c * 4);

    int p = p0;
    for (; p + 8 <= p1; p += 8) {
        int s0 = srcs[p + 0], s1 = srcs[p + 1], s2 = srcs[p + 2], s3 = srcs[p + 3];
        int s4 = srcs[p + 4], s5 = srcs[p + 5], s6 = srcs[p + 6], s7 = srcs[p + 7];
        float4 v0 = ld4(h0 + (size_t)s0 * HD + c * 4);
        float4 v1 = ld4(h0 + (size_t)s1 * HD + c * 4);
        float4 v2 = ld4(h0 + (size_t)s2 * HD + c * 4);
        float4 v3 = ld4(h0 + (size_t)s3 * HD + c * 4);
        float4 v4 = ld4(h0 + (size_t)s4 * HD + c * 4);
        float4 v5 = ld4(h0 + (size_t)s5 * HD + c * 4);
        float4 v6 = ld4(h0 + (size_t)s6 * HD + c * 4);
        float4 v7 = ld4(h0 + (size_t)s7 * HD + c * 4);
        acc = add4(acc, add4(add4(add4(v0, v1), add4(v2, v3)),
                             add4(add4(v4, v5), add4(v6, v7))));
    }
    for (; p + 4 <= p1; p += 4) {
        int s0 = srcs[p + 0], s1 = srcs[p + 1], s2 = srcs[p + 2], s3 = srcs[p + 3];
        float4 v0 = ld4(h0 + (size_t)s0 * HD + c * 4);
        float4 v1 = ld4(h0 + (size_t)s1 * HD + c * 4);
        float4 v2 = ld4(h0 + (size_t)s2 * HD + c * 4);
        float4 v3 = ld4(h0 + (size_t)s3 * HD + c * 4);
        acc = add4(acc, add4(add4(v0, v1), add4(v2, v3)));
    }
    for (; p < p1; ++p)
        acc = add4(acc, ld4(h0 + (size_t)srcs[p] * HD + c * 4));

    *(float4*)(z + (size_t)row * HD + c * 4) = acc;
}

__global__ void bn_finalize_kernel(const float* __restrict__ sum, const float* __restrict__ sumsq,
                                   const float* __restrict__ gamma, const float* __restrict__ beta,
                                   float* __restrict__ scale, float* __restrict__ shift)
{
    int f = threadIdx.x;
    if (f < HD) {
        float mean = sum[f] * (1.0f / NN);
        float var  = fmaxf(sumsq[f] * (1.0f / NN) - mean * mean, 0.0f);
        float rstd = rsqrtf(var + BN_EPS);
        float sc = rstd * gamma[f];
        scale[f] = sc;
        shift[f] = beta[f] - mean * sc;
    }
}

// ---------------- PairNorm: streaming float4, in place ----------------
__global__ __launch_bounds__(256) void pn_kernel(float* l1, const float* __restrict__ colsum,
                                                 const float* __restrict__ rowss)
{
    int idx = blockIdx.x * 256 + threadIdx.x;   // float4 index
    if (idx >= NN * 24) return;
    int row = idx / 24;
    int q = idx - row * 24;
    float rs = rsqrtf(1e-6f + rowss[row]);
    float4 v = ld4(l1 + (size_t)idx * 4);
    float4 cm = ld4(colsum + q * 4);
    v.x = PN_SCALE * v.x * rs - cm.x * (1.0f / NN);
    v.y = PN_SCALE * v.y * rs - cm.y * (1.0f / NN);
    v.z = PN_SCALE * v.z * rs - cm.z * (1.0f / NN);
    v.w = PN_SCALE * v.w * rs - cm.w * (1.0f / NN);
    *(float4*)(l1 + (size_t)idx * 4) = v;
}

extern "C" void kernel_launch(void* const* d_in, const int* in_sizes, int n_in,
                              void* d_out, int out_size, void* d_ws, size_t ws_size,
                              hipStream_t stream) {
    const float* x     = (const float*)d_in[0];
    const int*   ei    = (const int*)d_in[1];
    const float* W0    = (const float*)d_in[2];
    const float* b0    = (const float*)d_in[3];
    const float* W1    = (const float*)d_in[4];
    const float* b1    = (const float*)d_in[5];
    const float* gamma = (const float*)d_in[6];
    const float* beta  = (const float*)d_in[7];
    const float* W2    = (const float*)d_in[8];
    const float* b2    = (const float*)d_in[9];

    float* out_l1 = (float*)d_out;                 // [N,96]: z -> h -> l1 (in place)
    float* out_h0 = out_l1 + (size_t)NN * HD;      // [N,96]: h0 output

    float* stats   = (float*)d_ws;
    float* s_sum   = stats;            // 96
    float* s_sumsq = stats + HD;       // 96
    float* s_col   = stats + 2 * HD;   // 96
    float* s_scale = stats + 288;      // 96
    float* s_shift = stats + 384;      // 96
    float* rowss = stats + 1024;
    int* cnt    = (int*)(rowss + NN);
    int* rowptr = cnt + NN;
    int* bsum   = rowptr + NN + 2;
    int* srcs   = bsum + 256;

    const int E = in_sizes[1] / 2;                 // 800000
    const int GB = (NN + 63) / 64;                 // 782

    zero_kernel<<<(1024 + NN + 255) / 256, 256, 0, stream>>>(stats, cnt);
    // 1) h0 = x @ W0^T + b0, with edge histogram fused as prologue
    //    (782 blocks x 1024 edges covers E=800000; atomics drain under GEMM)
    gemm_tiled<IN_DIM, 0><<<GB, 256, 0, stream>>>(x, W0, b0, out_h0, nullptr, nullptr,
                                                  nullptr, nullptr, nullptr, nullptr,
                                                  ei + E, cnt, E);
    // 2) CSR build: hierarchical scan -> multipass fill
    scan_part1<<<SCAN_NB, 256, 0, stream>>>(cnt, bsum);
    scan_part2<<<1, 256, 0, stream>>>(bsum);
    scan_part3<<<SCAN_NB, 256, 0, stream>>>(cnt, bsum, rowptr);
    fill_kernel<<<(E / 2 + 255) / 256, 256, 0, stream>>>(ei, cnt, srcs, E);
    // 3) gather: z = h0 + segment_sum(h0[src])
    gather_kernel<<<(NN + 7) / 8, 192, 0, stream>>>(out_h0, rowptr, srcs, out_l1);
    // 4) h = z @ W1^T + b1 (in place) + fused BN stats
    gemm_tiled<HD, 1><<<GB, 256, 0, stream>>>(out_l1, W1, b1, out_l1, nullptr, nullptr,
                                              s_sum, s_sumsq, nullptr, nullptr,
                                              nullptr, nullptr, 0);
    bn_finalize_kernel<<<1, 128, 0, stream>>>(s_sum, s_sumsq, gamma, beta, s_scale, s_shift);
    // 5) l1 = relu(bn(h)) @ W2^T + b2 (in place) + fused PN stats
    gemm_tiled<HD, 2><<<GB, 256, 0, stream>>>(out_l1, W2, b2, out_l1, s_scale, s_shift,
                                              nullptr, nullptr, s_col, rowss,
                                              nullptr, nullptr, 0);
    // 6) PairNorm finalize (streaming, in place)
    pn_kernel<<<(NN * 24 + 255) / 256, 256, 0, stream>>>(out_l1, s_col, rowss);
}